// Round 18
// baseline (151.628 us; speedup 1.0000x reference)
//
#include <hip/hip_runtime.h>
#include <hip/hip_fp16.h>

#define BB    4
#define TE    1024
#define TD    512
#define HH    128
#define DTILE 4
#define TTILE 64
#define ESTR  (TE + 8)              // e_s row stride: breaks d-bank aliasing
#define LOG2E 1.4426950408889634f

typedef float f32x2 __attribute__((ext_vector_type(2)));

__device__ __forceinline__ f32x2 pk_fma(f32x2 a, f32x2 b, f32x2 c) {
    return __builtin_elementwise_fma(a, b, c);
}

// Accurate-enough tanh for the proj epilogue (786K elems, off the hot path).
__device__ __forceinline__ float tanh_eval(float x) {
    float e = __builtin_amdgcn_exp2f(2.0f * LOG2E * x);
    return 1.0f - 2.0f * __builtin_amdgcn_rcpf(e + 1.0f);
}

__device__ __forceinline__ f32x2 cvt2(unsigned int x) {
    __half2 h = *(__half2*)&x;
    float2 f = __half22float2(h);
    return (f32x2){f.x, f.y};
}

// ---------------------------------------------------------------------------
// Kernel 1: tiled projections. A = tanh(enc@W) stored as FP16; B = tanh(dec@U)
// stays FP32. (Unchanged from R17.)
// ---------------------------------------------------------------------------
__global__ __launch_bounds__(256) void proj_gemm(
    const float* __restrict__ enc, const float* __restrict__ dec,
    const float* __restrict__ Wa,  const float* __restrict__ Ua,
    __half* __restrict__ ta_h,     // [B*TE, H] fp16
    float* __restrict__ tb)        // [B*TD, H] fp32
{
    __shared__ float Xs[64 * 33];
    __shared__ float Ws[32 * 64];

    const int tid = threadIdx.x;
    const int rt = blockIdx.x >> 1, ch = blockIdx.x & 1;
    const int r0 = rt * 64, c0 = ch * 64;

    const float* X; const float* W; int rX0;
    const bool encPart = (r0 < BB * TE);
    if (encPart) { X = enc; W = Wa; rX0 = r0; }
    else         { X = dec; W = Ua; rX0 = r0 - BB * TE; }

    const int c4 = tid & 15;
    const int rg = tid >> 4;

    float4 a0 = {0,0,0,0}, a1 = a0, a2 = a0, a3 = a0;

    for (int kc = 0; kc < 4; ++kc) {
        #pragma unroll
        for (int i = 0; i < 2; ++i) {
            int idx = tid + i * 256;
            int r  = idx >> 3, k4 = idx & 7;
            *(float4*)&Xs[r * 33 + k4 * 4] =
                *(const float4*)&X[(rX0 + r) * HH + kc * 32 + k4 * 4];
            int kk = idx >> 4, cc = idx & 15;
            *(float4*)&Ws[kk * 64 + cc * 4] =
                *(const float4*)&W[(kc * 32 + kk) * HH + c0 + cc * 4];
        }
        __syncthreads();
        #pragma unroll 8
        for (int k = 0; k < 32; ++k) {
            float4 wv = *(const float4*)&Ws[k * 64 + c4 * 4];
            float x0 = Xs[(rg * 4 + 0) * 33 + k];
            float x1 = Xs[(rg * 4 + 1) * 33 + k];
            float x2 = Xs[(rg * 4 + 2) * 33 + k];
            float x3 = Xs[(rg * 4 + 3) * 33 + k];
            a0.x = fmaf(x0, wv.x, a0.x); a0.y = fmaf(x0, wv.y, a0.y);
            a0.z = fmaf(x0, wv.z, a0.z); a0.w = fmaf(x0, wv.w, a0.w);
            a1.x = fmaf(x1, wv.x, a1.x); a1.y = fmaf(x1, wv.y, a1.y);
            a1.z = fmaf(x1, wv.z, a1.z); a1.w = fmaf(x1, wv.w, a1.w);
            a2.x = fmaf(x2, wv.x, a2.x); a2.y = fmaf(x2, wv.y, a2.y);
            a2.z = fmaf(x2, wv.z, a2.z); a2.w = fmaf(x2, wv.w, a2.w);
            a3.x = fmaf(x3, wv.x, a3.x); a3.y = fmaf(x3, wv.y, a3.y);
            a3.z = fmaf(x3, wv.z, a3.z); a3.w = fmaf(x3, wv.w, a3.w);
        }
        __syncthreads();
    }

    float4 accs[4] = {a0, a1, a2, a3};
    #pragma unroll
    for (int j = 0; j < 4; ++j) {
        float4 o = accs[j];
        o.x = tanh_eval(o.x); o.y = tanh_eval(o.y);
        o.z = tanh_eval(o.z); o.w = tanh_eval(o.w);
        if (encPart) {
            __half h[4] = {__float2half_rn(o.x), __float2half_rn(o.y),
                           __float2half_rn(o.z), __float2half_rn(o.w)};
            *(uint2*)&ta_h[(size_t)(r0 + rg * 4 + j) * HH + c0 + c4 * 4] =
                *(uint2*)h;
        } else {
            *(float4*)&tb[(size_t)(rX0 + rg * 4 + j) * HH + c0 + c4 * 4] = o;
        }
    }
}

// ---------------------------------------------------------------------------
// Kernel 2: fused energies -> softmax -> context. R17 structure with BATCHED
// phase-1 reductions: iterations produce per-lane partials only (no shfl);
// every 8 iterations run 8 INDEPENDENT shuffle trees (ILP hides DS latency),
// then each of the 8 group-lanes writes one energy.
// ---------------------------------------------------------------------------
__global__ __launch_bounds__(512, 4) void attn_fused(
    const float* __restrict__ enc,     // [B, TE, H] raw fp32
    const __half* __restrict__ ta,     // [B*TE, H]  = tanh(W_s), fp16
    const float* __restrict__ tb,      // [B*TD, H]  = tanh(U_h), fp32
    const float* __restrict__ Va,      // [H]
    float* __restrict__ c_out,         // [B, TD, H]
    float* __restrict__ e_out)         // [B, TD, TE]
{
    __shared__ float e_s[DTILE * ESTR];     // 16.1 KB
    __shared__ float c_red[8 * DTILE * HH]; // 16 KB

    const int tid = threadIdx.x;
    const int l   = tid & 63;
    const int w   = tid >> 6;            // 0..7 (row-octet owner)
    const int b   = blockIdx.x >> 7;
    const int d0  = (blockIdx.x & 127) * DTILE;

    // ---------------- Phase 1: energies ----------------
    {
        const int g  = l >> 3;           // group 0..7
        const int hl = l & 7;            // h-run selector within group
        const int dl = g & 3;            // this group's decoder step
        const int rh = g >> 2;           // row parity

        // Lane h-coverage: run0 = [hl*8, hl*8+8), run1 = [64+hl*8, ..+8).
        const float* tbrow = tb + ((size_t)b * TD + d0 + dl) * HH;
        f32x2 Bv[8], Bp[8], Vv[8];
        #pragma unroll
        for (int s = 0; s < 8; ++s) {
            int h = (s < 4) ? (hl * 8 + 2 * s) : (64 + hl * 8 + 2 * (s - 4));
            Vv[s] = (f32x2){Va[h], Va[h + 1]};
            Bv[s] = (f32x2){tbrow[h], tbrow[h + 1]};
            Bp[s] = Vv[s] * Bv[s];
        }

        const __half* ta_b = ta + (size_t)b * TE * HH;

        // Wave w covers rows {(i>>2)*64 + w*8 + (i&3)*2 + rh}, i = 0..63.
        auto rowOf = [&](int i) {
            return ((i >> 2) << 6) + w * 8 + ((i & 3) << 1) + rh;
        };

        uint4 A0[2], A1[2];   // 2 x 8 halfs per buffer
        auto loadA = [&](int i, uint4 (&A)[2]) {
            const __half* base = ta_b + (size_t)rowOf(i) * HH;
            A[0] = *(const uint4*)(base + hl * 8);
            A[1] = *(const uint4*)(base + 64 + hl * 8);
        };

        // Per-lane partial energy (ends at rcp -- NO shuffles).
        auto p1p = [&](uint4 (&A)[2]) -> float {
            const f32x2 one2 = {1.0f, 1.0f};
            f32x2 n2[8], d2[8];
            unsigned int uu[8] = {A[0].x, A[0].y, A[0].z, A[0].w,
                                  A[1].x, A[1].y, A[1].z, A[1].w};
            #pragma unroll
            for (int s = 0; s < 8; ++s) {
                f32x2 Ax = cvt2(uu[s]);
                n2[s] = pk_fma(Vv[s], Ax, Bp[s]);
                d2[s] = pk_fma(Ax, Bv[s], one2);
            }
            #pragma unroll
            for (int s = 4; s >= 1; s >>= 1) {
                #pragma unroll
                for (int k = 0; k < s; ++k) {
                    n2[k] = pk_fma(n2[2 * k], d2[2 * k + 1], n2[2 * k + 1] * d2[2 * k]);
                    d2[k] = d2[2 * k] * d2[2 * k + 1];
                }
            }
            float num = n2[0].x * d2[0].y + n2[0].y * d2[0].x;
            float den = d2[0].x * d2[0].y;
            return num * __builtin_amdgcn_rcpf(den);
        };

        float ep[8];
        loadA(0, A0);
        #pragma unroll 1
        for (int base = 0; base < 64; base += 8) {
            // 8 iterations -> 8 per-lane partials (pingpong prefetch).
            #pragma unroll
            for (int k = 0; k < 8; ++k) {
                int i = base + k;
                if (i < 63) {
                    if (k & 1) loadA(i + 1, A0);
                    else       loadA(i + 1, A1);
                }
                ep[k] = p1p((k & 1) ? A1 : A0);
            }
            // 8 independent 3-level shuffle trees (ILP hides DS latency).
            #pragma unroll
            for (int k = 0; k < 8; ++k) ep[k] += __shfl_xor(ep[k], 1);
            #pragma unroll
            for (int k = 0; k < 8; ++k) ep[k] += __shfl_xor(ep[k], 2);
            #pragma unroll
            for (int k = 0; k < 8; ++k) ep[k] += __shfl_xor(ep[k], 4);
            // All 8 group-lanes now hold all 8 sums; lane hl writes sum hl.
            float myE = hl == 0 ? ep[0] : hl == 1 ? ep[1] : hl == 2 ? ep[2]
                      : hl == 3 ? ep[3] : hl == 4 ? ep[4] : hl == 5 ? ep[5]
                      : hl == 6 ? ep[6] : ep[7];
            e_s[dl * ESTR + rowOf(base + hl)] = myE;
        }
    }
    __syncthreads();   // all waves' raw energies visible

    // ---------------- Phase 2: softmax (d = w&3, two waves split halves) ----
    {
        const int d2 = w & 3, hf = w >> 2;
        float ev[16];
        float m = -3.0e38f;
        #pragma unroll
        for (int i = 0; i < 16; ++i) {
            ev[i] = e_s[d2 * ESTR + i * 64 + l];
            m = fmaxf(m, ev[i]);
        }
        #pragma unroll
        for (int off = 32; off; off >>= 1) m = fmaxf(m, __shfl_xor(m, off));
        float s = 0.f;
        #pragma unroll
        for (int i = 0; i < 16; ++i) {
            ev[i] = __builtin_amdgcn_exp2f((ev[i] - m) * LOG2E);
            s += ev[i];
        }
        #pragma unroll
        for (int off = 32; off; off >>= 1) s += __shfl_xor(s, off);
        float inv = __builtin_amdgcn_rcpf(s);

        __syncthreads();   // all raw-energy reads done before overwrite
        float* eo = e_out + ((size_t)b * TD + d0 + d2) * TE;
        #pragma unroll
        for (int i = 0; i < 8; ++i) {
            int ii = hf * 8 + i;
            float p = ev[ii] * inv;
            e_s[d2 * ESTR + ii * 64 + l] = p;
            eo[ii * 64 + l] = p;
        }
        __syncthreads();   // normalized p visible to all waves
    }

    // ---------------- Phase 3: context (packed FMAs, register pingpong) -----
    const int h4 = l & 31, tsub = l >> 5;
    f32x2 accL[DTILE], accH[DTILE];
    #pragma unroll
    for (int d = 0; d < DTILE; ++d) {
        accL[d] = (f32x2){0.f, 0.f};
        accH[d] = (f32x2){0.f, 0.f};
    }

    {
        const float* enc_w = enc + ((size_t)b * TE + w * 8) * HH;
        float4 X0[4], X1[4];

        auto loadX = [&](int tt, float4 (&X)[4]) {
            const float* base = enc_w + (size_t)tt * TTILE * HH;
            #pragma unroll
            for (int k = 0; k < 4; ++k)
                X[k] = *(const float4*)&base[(tsub * 4 + k) * HH + h4 * 4];
        };

        auto p3c = [&](int tt, float4 (&X)[4]) {
            float4 ep4[DTILE];
            #pragma unroll
            for (int d = 0; d < DTILE; ++d)
                ep4[d] = *(const float4*)&e_s[d * ESTR + tt * TTILE + w * 8 + tsub * 4];
            #pragma unroll
            for (int k = 0; k < 4; ++k) {
                f32x2 xL = (f32x2){X[k].x, X[k].y};
                f32x2 xH = (f32x2){X[k].z, X[k].w};
                #pragma unroll
                for (int d = 0; d < DTILE; ++d) {
                    float p = k == 0 ? ep4[d].x : k == 1 ? ep4[d].y
                            : k == 2 ? ep4[d].z : ep4[d].w;
                    f32x2 pv = (f32x2){p, p};
                    accL[d] = pk_fma(pv, xL, accL[d]);
                    accH[d] = pk_fma(pv, xH, accH[d]);
                }
            }
        };

        loadX(0, X0);
        #pragma unroll 1
        for (int tt = 0; tt < 14; tt += 2) {
            loadX(tt + 1, X1);
            p3c(tt, X0);
            loadX(tt + 2, X0);
            p3c(tt + 1, X1);
        }
        loadX(15, X1);
        p3c(14, X0);
        p3c(15, X1);
    }

    // Combine tsub halves; park per-wave partials; tree-reduce across waves.
    float4 acc4[DTILE];
    #pragma unroll
    for (int d = 0; d < DTILE; ++d)
        acc4[d] = make_float4(accL[d].x, accL[d].y, accH[d].x, accH[d].y);
    #pragma unroll
    for (int d = 0; d < DTILE; ++d) {
        acc4[d].x += __shfl_xor(acc4[d].x, 32);
        acc4[d].y += __shfl_xor(acc4[d].y, 32);
        acc4[d].z += __shfl_xor(acc4[d].z, 32);
        acc4[d].w += __shfl_xor(acc4[d].w, 32);
    }
    if (tsub == 0) {
        #pragma unroll
        for (int d = 0; d < DTILE; ++d)
            *(float4*)&c_red[(w * DTILE + d) * HH + h4 * 4] = acc4[d];
    }
    __syncthreads();

    if (w < DTILE && l < 32) {
        float4 o = make_float4(0.f, 0.f, 0.f, 0.f);
        #pragma unroll
        for (int ww = 0; ww < 8; ++ww) {
            float4 p = *(const float4*)&c_red[(ww * DTILE + w) * HH + l * 4];
            o.x += p.x; o.y += p.y; o.z += p.z; o.w += p.w;
        }
        *(float4*)&c_out[((size_t)b * TD + d0 + w) * HH + l * 4] = o;
    }
}

// ---------------------------------------------------------------------------
extern "C" void kernel_launch(void* const* d_in, const int* in_sizes, int n_in,
                              void* d_out, int out_size, void* d_ws, size_t ws_size,
                              hipStream_t stream) {
    (void)in_sizes; (void)n_in; (void)out_size; (void)ws_size;

    const float* enc = (const float*)d_in[0];
    const float* dec = (const float*)d_in[1];
    const float* Wa  = (const float*)d_in[2];
    const float* Ua  = (const float*)d_in[3];
    const float* Va  = (const float*)d_in[4];

    float* c_out = (float*)d_out;
    float* e_out = (float*)d_out + BB * TD * HH;

    __half* ta_h = (__half*)d_ws;                               // 1 MB fp16
    float*  tb_p = (float*)((char*)d_ws + (size_t)BB * TE * HH * sizeof(__half));

    proj_gemm<<<192, 256, 0, stream>>>(enc, dec, Wa, Ua, ta_h, tb_p);
    attn_fused<<<(BB * TD) / DTILE, 512, 0, stream>>>(enc, ta_h, tb_p, Va, c_out, e_out);
}

// Round 19
// 123.268 us; speedup vs baseline: 1.2301x; 1.2301x over previous
//
#include <hip/hip_runtime.h>
#include <hip/hip_fp16.h>

#define BB    4
#define TE    1024
#define TD    512
#define HH    128
#define DTILE 4
#define TTILE 64
#define ESTR  (TE + 8)              // e_s row stride: breaks d-bank aliasing
#define LOG2E 1.4426950408889634f

typedef float f32x2 __attribute__((ext_vector_type(2)));

__device__ __forceinline__ f32x2 pk_fma(f32x2 a, f32x2 b, f32x2 c) {
    return __builtin_elementwise_fma(a, b, c);
}

// Accurate-enough tanh for the proj epilogue (786K elems, off the hot path).
__device__ __forceinline__ float tanh_eval(float x) {
    float e = __builtin_amdgcn_exp2f(2.0f * LOG2E * x);
    return 1.0f - 2.0f * __builtin_amdgcn_rcpf(e + 1.0f);
}

__device__ __forceinline__ f32x2 cvt2(unsigned int x) {
    __half2 h = *(__half2*)&x;
    float2 f = __half22float2(h);
    return (f32x2){f.x, f.y};
}

// ---------------------------------------------------------------------------
// Kernel 1: tiled projections. A = tanh(enc@W) stored as FP16; B = tanh(dec@U)
// stays FP32. (Unchanged from R17.)
// ---------------------------------------------------------------------------
__global__ __launch_bounds__(256) void proj_gemm(
    const float* __restrict__ enc, const float* __restrict__ dec,
    const float* __restrict__ Wa,  const float* __restrict__ Ua,
    __half* __restrict__ ta_h,     // [B*TE, H] fp16
    float* __restrict__ tb)        // [B*TD, H] fp32
{
    __shared__ float Xs[64 * 33];
    __shared__ float Ws[32 * 64];

    const int tid = threadIdx.x;
    const int rt = blockIdx.x >> 1, ch = blockIdx.x & 1;
    const int r0 = rt * 64, c0 = ch * 64;

    const float* X; const float* W; int rX0;
    const bool encPart = (r0 < BB * TE);
    if (encPart) { X = enc; W = Wa; rX0 = r0; }
    else         { X = dec; W = Ua; rX0 = r0 - BB * TE; }

    const int c4 = tid & 15;
    const int rg = tid >> 4;

    float4 a0 = {0,0,0,0}, a1 = a0, a2 = a0, a3 = a0;

    for (int kc = 0; kc < 4; ++kc) {
        #pragma unroll
        for (int i = 0; i < 2; ++i) {
            int idx = tid + i * 256;
            int r  = idx >> 3, k4 = idx & 7;
            *(float4*)&Xs[r * 33 + k4 * 4] =
                *(const float4*)&X[(rX0 + r) * HH + kc * 32 + k4 * 4];
            int kk = idx >> 4, cc = idx & 15;
            *(float4*)&Ws[kk * 64 + cc * 4] =
                *(const float4*)&W[(kc * 32 + kk) * HH + c0 + cc * 4];
        }
        __syncthreads();
        #pragma unroll 8
        for (int k = 0; k < 32; ++k) {
            float4 wv = *(const float4*)&Ws[k * 64 + c4 * 4];
            float x0 = Xs[(rg * 4 + 0) * 33 + k];
            float x1 = Xs[(rg * 4 + 1) * 33 + k];
            float x2 = Xs[(rg * 4 + 2) * 33 + k];
            float x3 = Xs[(rg * 4 + 3) * 33 + k];
            a0.x = fmaf(x0, wv.x, a0.x); a0.y = fmaf(x0, wv.y, a0.y);
            a0.z = fmaf(x0, wv.z, a0.z); a0.w = fmaf(x0, wv.w, a0.w);
            a1.x = fmaf(x1, wv.x, a1.x); a1.y = fmaf(x1, wv.y, a1.y);
            a1.z = fmaf(x1, wv.z, a1.z); a1.w = fmaf(x1, wv.w, a1.w);
            a2.x = fmaf(x2, wv.x, a2.x); a2.y = fmaf(x2, wv.y, a2.y);
            a2.z = fmaf(x2, wv.z, a2.z); a2.w = fmaf(x2, wv.w, a2.w);
            a3.x = fmaf(x3, wv.x, a3.x); a3.y = fmaf(x3, wv.y, a3.y);
            a3.z = fmaf(x3, wv.z, a3.z); a3.w = fmaf(x3, wv.w, a3.w);
        }
        __syncthreads();
    }

    float4 accs[4] = {a0, a1, a2, a3};
    #pragma unroll
    for (int j = 0; j < 4; ++j) {
        float4 o = accs[j];
        o.x = tanh_eval(o.x); o.y = tanh_eval(o.y);
        o.z = tanh_eval(o.z); o.w = tanh_eval(o.w);
        if (encPart) {
            __half h[4] = {__float2half_rn(o.x), __float2half_rn(o.y),
                           __float2half_rn(o.z), __float2half_rn(o.w)};
            *(uint2*)&ta_h[(size_t)(r0 + rg * 4 + j) * HH + c0 + c4 * 4] =
                *(uint2*)h;
        } else {
            *(float4*)&tb[(size_t)(rX0 + rg * 4 + j) * HH + c0 + c4 * 4] = o;
        }
    }
}

// ---------------------------------------------------------------------------
// Kernel 2: fused energies -> softmax -> context. R17 structure with
// BATCH-4 phase-1 reductions: 4 per-lane partials per batch, then 4
// INDEPENDENT shuffle trees (4-way ILP on the DS chain), then lanes hl<4
// each write one energy. Small enough live set to avoid R18's spill.
// ---------------------------------------------------------------------------
__global__ __launch_bounds__(512, 4) void attn_fused(
    const float* __restrict__ enc,     // [B, TE, H] raw fp32
    const __half* __restrict__ ta,     // [B*TE, H]  = tanh(W_s), fp16
    const float* __restrict__ tb,      // [B*TD, H]  = tanh(U_h), fp32
    const float* __restrict__ Va,      // [H]
    float* __restrict__ c_out,         // [B, TD, H]
    float* __restrict__ e_out)         // [B, TD, TE]
{
    __shared__ float e_s[DTILE * ESTR];     // 16.1 KB
    __shared__ float c_red[8 * DTILE * HH]; // 16 KB

    const int tid = threadIdx.x;
    const int l   = tid & 63;
    const int w   = tid >> 6;            // 0..7 (row-octet owner)
    const int b   = blockIdx.x >> 7;
    const int d0  = (blockIdx.x & 127) * DTILE;

    // ---------------- Phase 1: energies ----------------
    {
        const int g  = l >> 3;           // group 0..7
        const int hl = l & 7;            // h-run selector within group
        const int dl = g & 3;            // this group's decoder step
        const int rh = g >> 2;           // row parity

        // Lane h-coverage: run0 = [hl*8, hl*8+8), run1 = [64+hl*8, ..+8).
        const float* tbrow = tb + ((size_t)b * TD + d0 + dl) * HH;
        f32x2 Bv[8], Bp[8], Vv[8];
        #pragma unroll
        for (int s = 0; s < 8; ++s) {
            int h = (s < 4) ? (hl * 8 + 2 * s) : (64 + hl * 8 + 2 * (s - 4));
            Vv[s] = (f32x2){Va[h], Va[h + 1]};
            Bv[s] = (f32x2){tbrow[h], tbrow[h + 1]};
            Bp[s] = Vv[s] * Bv[s];
        }

        const __half* ta_b = ta + (size_t)b * TE * HH;

        // Wave w covers rows {(i>>2)*64 + w*8 + (i&3)*2 + rh}, i = 0..63.
        auto rowOf = [&](int i) {
            return ((i >> 2) << 6) + w * 8 + ((i & 3) << 1) + rh;
        };

        uint4 A0[2], A1[2];   // 2 x 8 halfs per buffer
        auto loadA = [&](int i, uint4 (&A)[2]) {
            const __half* base = ta_b + (size_t)rowOf(i) * HH;
            A[0] = *(const uint4*)(base + hl * 8);
            A[1] = *(const uint4*)(base + 64 + hl * 8);
        };

        // Per-lane partial energy (ends at rcp -- NO shuffles).
        auto p1p = [&](uint4 (&A)[2]) -> float {
            const f32x2 one2 = {1.0f, 1.0f};
            f32x2 n2[8], d2[8];
            unsigned int uu[8] = {A[0].x, A[0].y, A[0].z, A[0].w,
                                  A[1].x, A[1].y, A[1].z, A[1].w};
            #pragma unroll
            for (int s = 0; s < 8; ++s) {
                f32x2 Ax = cvt2(uu[s]);
                n2[s] = pk_fma(Vv[s], Ax, Bp[s]);
                d2[s] = pk_fma(Ax, Bv[s], one2);
            }
            #pragma unroll
            for (int s = 4; s >= 1; s >>= 1) {
                #pragma unroll
                for (int k = 0; k < s; ++k) {
                    n2[k] = pk_fma(n2[2 * k], d2[2 * k + 1], n2[2 * k + 1] * d2[2 * k]);
                    d2[k] = d2[2 * k] * d2[2 * k + 1];
                }
            }
            float num = n2[0].x * d2[0].y + n2[0].y * d2[0].x;
            float den = d2[0].x * d2[0].y;
            return num * __builtin_amdgcn_rcpf(den);
        };

        float ep0, ep1, ep2, ep3;
        loadA(0, A0);
        #pragma unroll 1
        for (int base = 0; base < 64; base += 4) {
            // 4 iterations -> 4 per-lane partials (pingpong prefetch).
            if (base + 1 < 64) loadA(base + 1, A1);
            ep0 = p1p(A0);
            if (base + 2 < 64) loadA(base + 2, A0);
            ep1 = p1p(A1);
            if (base + 3 < 64) loadA(base + 3, A1);
            ep2 = p1p(A0);
            if (base + 4 < 64) loadA(base + 4, A0);
            ep3 = p1p(A1);
            // 4 independent 3-level shuffle trees (ILP hides DS latency).
            ep0 += __shfl_xor(ep0, 1);
            ep1 += __shfl_xor(ep1, 1);
            ep2 += __shfl_xor(ep2, 1);
            ep3 += __shfl_xor(ep3, 1);
            ep0 += __shfl_xor(ep0, 2);
            ep1 += __shfl_xor(ep1, 2);
            ep2 += __shfl_xor(ep2, 2);
            ep3 += __shfl_xor(ep3, 2);
            ep0 += __shfl_xor(ep0, 4);
            ep1 += __shfl_xor(ep1, 4);
            ep2 += __shfl_xor(ep2, 4);
            ep3 += __shfl_xor(ep3, 4);
            // Lanes hl = 0..3 write sums 0..3 of this batch.
            float myE = hl == 0 ? ep0 : hl == 1 ? ep1 : hl == 2 ? ep2 : ep3;
            if (hl < 4) e_s[dl * ESTR + rowOf(base + hl)] = myE;
        }
    }
    __syncthreads();   // all waves' raw energies visible

    // ---------------- Phase 2: softmax (d = w&3, two waves split halves) ----
    {
        const int d2 = w & 3, hf = w >> 2;
        float ev[16];
        float m = -3.0e38f;
        #pragma unroll
        for (int i = 0; i < 16; ++i) {
            ev[i] = e_s[d2 * ESTR + i * 64 + l];
            m = fmaxf(m, ev[i]);
        }
        #pragma unroll
        for (int off = 32; off; off >>= 1) m = fmaxf(m, __shfl_xor(m, off));
        float s = 0.f;
        #pragma unroll
        for (int i = 0; i < 16; ++i) {
            ev[i] = __builtin_amdgcn_exp2f((ev[i] - m) * LOG2E);
            s += ev[i];
        }
        #pragma unroll
        for (int off = 32; off; off >>= 1) s += __shfl_xor(s, off);
        float inv = __builtin_amdgcn_rcpf(s);

        __syncthreads();   // all raw-energy reads done before overwrite
        float* eo = e_out + ((size_t)b * TD + d0 + d2) * TE;
        #pragma unroll
        for (int i = 0; i < 8; ++i) {
            int ii = hf * 8 + i;
            float p = ev[ii] * inv;
            e_s[d2 * ESTR + ii * 64 + l] = p;
            eo[ii * 64 + l] = p;
        }
        __syncthreads();   // normalized p visible to all waves
    }

    // ---------------- Phase 3: context (packed FMAs, register pingpong) -----
    const int h4 = l & 31, tsub = l >> 5;
    f32x2 accL[DTILE], accH[DTILE];
    #pragma unroll
    for (int d = 0; d < DTILE; ++d) {
        accL[d] = (f32x2){0.f, 0.f};
        accH[d] = (f32x2){0.f, 0.f};
    }

    {
        const float* enc_w = enc + ((size_t)b * TE + w * 8) * HH;
        float4 X0[4], X1[4];

        auto loadX = [&](int tt, float4 (&X)[4]) {
            const float* base = enc_w + (size_t)tt * TTILE * HH;
            #pragma unroll
            for (int k = 0; k < 4; ++k)
                X[k] = *(const float4*)&base[(tsub * 4 + k) * HH + h4 * 4];
        };

        auto p3c = [&](int tt, float4 (&X)[4]) {
            float4 ep4[DTILE];
            #pragma unroll
            for (int d = 0; d < DTILE; ++d)
                ep4[d] = *(const float4*)&e_s[d * ESTR + tt * TTILE + w * 8 + tsub * 4];
            #pragma unroll
            for (int k = 0; k < 4; ++k) {
                f32x2 xL = (f32x2){X[k].x, X[k].y};
                f32x2 xH = (f32x2){X[k].z, X[k].w};
                #pragma unroll
                for (int d = 0; d < DTILE; ++d) {
                    float p = k == 0 ? ep4[d].x : k == 1 ? ep4[d].y
                            : k == 2 ? ep4[d].z : ep4[d].w;
                    f32x2 pv = (f32x2){p, p};
                    accL[d] = pk_fma(pv, xL, accL[d]);
                    accH[d] = pk_fma(pv, xH, accH[d]);
                }
            }
        };

        loadX(0, X0);
        #pragma unroll 1
        for (int tt = 0; tt < 14; tt += 2) {
            loadX(tt + 1, X1);
            p3c(tt, X0);
            loadX(tt + 2, X0);
            p3c(tt + 1, X1);
        }
        loadX(15, X1);
        p3c(14, X0);
        p3c(15, X1);
    }

    // Combine tsub halves; park per-wave partials; tree-reduce across waves.
    float4 acc4[DTILE];
    #pragma unroll
    for (int d = 0; d < DTILE; ++d)
        acc4[d] = make_float4(accL[d].x, accL[d].y, accH[d].x, accH[d].y);
    #pragma unroll
    for (int d = 0; d < DTILE; ++d) {
        acc4[d].x += __shfl_xor(acc4[d].x, 32);
        acc4[d].y += __shfl_xor(acc4[d].y, 32);
        acc4[d].z += __shfl_xor(acc4[d].z, 32);
        acc4[d].w += __shfl_xor(acc4[d].w, 32);
    }
    if (tsub == 0) {
        #pragma unroll
        for (int d = 0; d < DTILE; ++d)
            *(float4*)&c_red[(w * DTILE + d) * HH + h4 * 4] = acc4[d];
    }
    __syncthreads();

    if (w < DTILE && l < 32) {
        float4 o = make_float4(0.f, 0.f, 0.f, 0.f);
        #pragma unroll
        for (int ww = 0; ww < 8; ++ww) {
            float4 p = *(const float4*)&c_red[(ww * DTILE + w) * HH + l * 4];
            o.x += p.x; o.y += p.y; o.z += p.z; o.w += p.w;
        }
        *(float4*)&c_out[((size_t)b * TD + d0 + w) * HH + l * 4] = o;
    }
}

// ---------------------------------------------------------------------------
extern "C" void kernel_launch(void* const* d_in, const int* in_sizes, int n_in,
                              void* d_out, int out_size, void* d_ws, size_t ws_size,
                              hipStream_t stream) {
    (void)in_sizes; (void)n_in; (void)out_size; (void)ws_size;

    const float* enc = (const float*)d_in[0];
    const float* dec = (const float*)d_in[1];
    const float* Wa  = (const float*)d_in[2];
    const float* Ua  = (const float*)d_in[3];
    const float* Va  = (const float*)d_in[4];

    float* c_out = (float*)d_out;
    float* e_out = (float*)d_out + BB * TD * HH;

    __half* ta_h = (__half*)d_ws;                               // 1 MB fp16
    float*  tb_p = (float*)((char*)d_ws + (size_t)BB * TE * HH * sizeof(__half));

    proj_gemm<<<192, 256, 0, stream>>>(enc, dec, Wa, Ua, ta_h, tb_p);
    attn_fused<<<(BB * TD) / DTILE, 512, 0, stream>>>(enc, ta_h, tb_p, Va, c_out, e_out);
}